// Round 1
// baseline (253.644 us; speedup 1.0000x reference)
//
#include <hip/hip_runtime.h>

typedef unsigned short u16;
typedef __bf16 bf16x8 __attribute__((ext_vector_type(8)));
typedef float f32x4 __attribute__((ext_vector_type(4)));
typedef unsigned short u16x8 __attribute__((ext_vector_type(8)));

#define NPIX 25088
#define HW 3136

static __device__ __forceinline__ u16 f2bf(float f) {
  // round-to-nearest-even f32 -> bf16 (no NaN/inf in this workload)
  unsigned u = __builtin_bit_cast(unsigned, f);
  return (u16)((u + 0x7fffu + ((u >> 16) & 1u)) >> 16);
}

// ---------------------------------------------------------------------------
// Kernel 1: blocks [0,98)   -> p1 = W1 @ x1 per pixel, stored fp32 transposed P1T[c][pixel]
//           blocks [98,196) -> p2 = W2 @ x2 per pixel, stored bf16 P2b[pixel][d]
//           blocks [196,708)-> Wp fp32 -> bf16 copy, layout [o][c*64+d] (k-contiguous)
// ---------------------------------------------------------------------------
__global__ __launch_bounds__(256) void proj_kernel(
    const float* __restrict__ x1, const float* __restrict__ x2,
    const float* __restrict__ W1, const float* __restrict__ W2,
    const float* __restrict__ Wp,
    float* __restrict__ P1T, u16* __restrict__ P2b, u16* __restrict__ Wpb)
{
  const int blk = blockIdx.x;
  const int t = threadIdx.x;

  if (blk >= 196) {  // Wp conversion: 512 blocks * 256 thr * 8 elems = 1048576
    const long base = (long)(blk - 196) * 2048 + (long)t * 8;
    f32x4 a = *(const f32x4*)(Wp + base);
    f32x4 b = *(const f32x4*)(Wp + base + 4);
    u16x8 o;
    o[0]=f2bf(a[0]); o[1]=f2bf(a[1]); o[2]=f2bf(a[2]); o[3]=f2bf(a[3]);
    o[4]=f2bf(b[0]); o[5]=f2bf(b[1]); o[6]=f2bf(b[2]); o[7]=f2bf(b[3]);
    *(u16x8*)(Wpb + base) = o;
    return;
  }

  const bool isP1 = blk < 98;
  const float* __restrict__ x = isP1 ? x1 : x2;
  const float* __restrict__ W = isP1 ? W1 : W2;

  __shared__ float WT[128 * 64];  // WT[c][m] = W[m][c]
  for (int idx = t; idx < 8192; idx += 256)
    WT[(idx & 127) * 64 + (idx >> 7)] = W[idx];
  __syncthreads();

  const int p = (isP1 ? blk : blk - 98) * 256 + t;   // one pixel per thread
  const int b = p / HW;
  const int hw = p - b * HW;
  const float* xp = x + (long)b * 128 * HW + hw;

  float acc[64];
  #pragma unroll
  for (int m = 0; m < 64; ++m) acc[m] = 0.f;

  for (int c = 0; c < 128; ++c) {
    float xv = xp[(long)c * HW];            // coalesced across lanes
    #pragma unroll
    for (int g = 0; g < 16; ++g) {
      f32x4 wv = *(const f32x4*)&WT[c * 64 + g * 4];  // broadcast read
      acc[g*4+0] = fmaf(xv, wv[0], acc[g*4+0]);
      acc[g*4+1] = fmaf(xv, wv[1], acc[g*4+1]);
      acc[g*4+2] = fmaf(xv, wv[2], acc[g*4+2]);
      acc[g*4+3] = fmaf(xv, wv[3], acc[g*4+3]);
    }
  }

  if (isP1) {
    #pragma unroll
    for (int m = 0; m < 64; ++m)
      P1T[(long)m * NPIX + p] = acc[m];     // coalesced per m
  } else {
    #pragma unroll
    for (int g = 0; g < 8; ++g) {
      u16x8 v;
      #pragma unroll
      for (int j = 0; j < 8; ++j) v[j] = f2bf(acc[g*8+j]);
      *(u16x8*)(P2b + (long)p * 64 + g * 8) = v;
    }
  }
}

// ---------------------------------------------------------------------------
// Kernel 2: per block: 64 pixels x 256 outputs. 8 waves, wave w owns o in [w*32, w*32+32).
// K-loop over c (64 iters): S_c = P2tile @ Wp[:,c,:]^T via 16 MFMA(16x16x32 bf16),
// acc += p1[:,c] (*) S_c  (fp32 fmac). Epilogue: fused LayerNorm + erf-GELU +
// LDS transpose for coalesced NCHW store.
// ---------------------------------------------------------------------------
__global__ __launch_bounds__(512, 2) void bilinear_kernel(
    const float* __restrict__ P1T, const u16* __restrict__ P2b,
    const u16* __restrict__ Wpb, const float* __restrict__ gamma,
    const float* __restrict__ beta, float* __restrict__ out)
{
  __shared__ __align__(16) unsigned char smem[37376];
  u16*   P2s  = (u16*)smem;               // [64 pix][64 d] bf16   (8192 B)
  float* P1Ts = (float*)(smem + 8192);    // [64 c][64 pix] f32    (16384 B)
  float* tbuf = (float*)smem;             // [8 w][16][65] f32, overlaps staging (33280 B)
  float* ssum = (float*)(smem + 33280);   // [64 pix][8 w]         (2048 B)
  float* ssq  = (float*)(smem + 35328);   // [64 pix][8 w]         (2048 B)

  const int t = threadIdx.x;
  const int w = t >> 6;
  const int lane = t & 63;
  const int l15 = lane & 15;
  const int l4 = lane >> 4;
  const int P0 = blockIdx.x * 64;

  // ---- stage P2 tile (bf16) and P1T tile (f32) into LDS
  {
    const int row = t >> 3;
    const int col = (t & 7) * 8;
    *(u16x8*)&P2s[row * 64 + col] = *(const u16x8*)(P2b + (long)(P0 + row) * 64 + col);
    const float* src = P1T + (long)row * NPIX + P0 + col;
    *(f32x4*)&P1Ts[row * 64 + col]     = *(const f32x4*)src;
    *(f32x4*)&P1Ts[row * 64 + col + 4] = *(const f32x4*)(src + 4);
  }
  __syncthreads();

  // ---- A fragments (p2), loaded ONCE, reused across all 64 c-slices
  // A layout: row(pixel)=l&15, k = 8*(l>>4)+j (+32*ks)
  bf16x8 afr[4][2];
  #pragma unroll
  for (int m = 0; m < 4; ++m)
    #pragma unroll
    for (int ks = 0; ks < 2; ++ks)
      afr[m][ks] = __builtin_bit_cast(bf16x8,
          *(const u16x8*)&P2s[(m * 16 + l15) * 64 + ks * 32 + l4 * 8]);

  // B fragment base: col(o)=l&15, k-contiguous 8 at 8*(l>>4); Wpb row = o, 4096 k's
  const u16* wp = Wpb + (long)(w * 32 + l15) * 4096 + l4 * 8;

  const f32x4 zero4 = {0.f, 0.f, 0.f, 0.f};
  f32x4 acc[4][2];
  #pragma unroll
  for (int m = 0; m < 4; ++m)
    #pragma unroll
    for (int n = 0; n < 2; ++n) acc[m][n] = zero4;

  // software-pipelined B loads (L2-resident Wpb)
  u16x8 bcur[2][2];
  bcur[0][0] = *(const u16x8*)(wp);
  bcur[0][1] = *(const u16x8*)(wp + 32);
  bcur[1][0] = *(const u16x8*)(wp + 65536);
  bcur[1][1] = *(const u16x8*)(wp + 65536 + 32);

  for (int c = 0; c < 64; ++c) {
    const u16* wpn = wp + ((c + 1) & 63) * 64;
    u16x8 bnxt[2][2];
    bnxt[0][0] = *(const u16x8*)(wpn);
    bnxt[0][1] = *(const u16x8*)(wpn + 32);
    bnxt[1][0] = *(const u16x8*)(wpn + 65536);
    bnxt[1][1] = *(const u16x8*)(wpn + 65536 + 32);

    f32x4 p1v[4];   // fp32 p1 for D-rows: pixel = m*16 + 4*(l>>4) + r
    #pragma unroll
    for (int m = 0; m < 4; ++m)
      p1v[m] = *(const f32x4*)&P1Ts[c * 64 + m * 16 + l4 * 4];

    #pragma unroll
    for (int m = 0; m < 4; ++m) {
      #pragma unroll
      for (int n = 0; n < 2; ++n) {
        f32x4 s = zero4;
        s = __builtin_amdgcn_mfma_f32_16x16x32_bf16(afr[m][0],
              __builtin_bit_cast(bf16x8, bcur[n][0]), s, 0, 0, 0);
        s = __builtin_amdgcn_mfma_f32_16x16x32_bf16(afr[m][1],
              __builtin_bit_cast(bf16x8, bcur[n][1]), s, 0, 0, 0);
        #pragma unroll
        for (int r = 0; r < 4; ++r)
          acc[m][n][r] = fmaf(p1v[m][r], s[r], acc[m][n][r]);
      }
    }
    #pragma unroll
    for (int n = 0; n < 2; ++n)
      #pragma unroll
      for (int ks = 0; ks < 2; ++ks)
        bcur[n][ks] = bnxt[n][ks];
  }

  // ---- LayerNorm stats: per-lane partials over this wave's 32 o's
  float psum[4][4], psq[4][4];
  #pragma unroll
  for (int m = 0; m < 4; ++m)
    #pragma unroll
    for (int r = 0; r < 4; ++r) {
      float a0 = acc[m][0][r], a1 = acc[m][1][r];
      psum[m][r] = a0 + a1;
      psq[m][r]  = a0 * a0 + a1 * a1;
    }
  #pragma unroll
  for (int mask = 1; mask < 16; mask <<= 1) {
    #pragma unroll
    for (int m = 0; m < 4; ++m)
      #pragma unroll
      for (int r = 0; r < 4; ++r) {
        psum[m][r] += __shfl_xor(psum[m][r], mask);
        psq[m][r]  += __shfl_xor(psq[m][r], mask);
      }
  }
  if (l15 == 0) {
    #pragma unroll
    for (int m = 0; m < 4; ++m)
      #pragma unroll
      for (int r = 0; r < 4; ++r) {
        const int pix = m * 16 + l4 * 4 + r;
        ssum[pix * 8 + w] = psum[m][r];
        ssq[pix * 8 + w]  = psq[m][r];
      }
  }
  __syncthreads();

  float mean[4][4], rstd[4][4];
  #pragma unroll
  for (int m = 0; m < 4; ++m)
    #pragma unroll
    for (int r = 0; r < 4; ++r) {
      const int pix = m * 16 + l4 * 4 + r;
      float s = 0.f, q = 0.f;
      #pragma unroll
      for (int wv = 0; wv < 8; ++wv) { s += ssum[pix * 8 + wv]; q += ssq[pix * 8 + wv]; }
      float mu = s * (1.f / 256.f);
      float var = q * (1.f / 256.f) - mu * mu;
      mean[m][r] = mu;
      rstd[m][r] = rsqrtf(var + 1e-5f);
    }

  const int bidx = P0 / HW;
  const int hw0 = P0 - bidx * HW;
  float gam[2], bet[2];
  #pragma unroll
  for (int n = 0; n < 2; ++n) {
    gam[n] = gamma[w * 32 + n * 16 + l15];
    bet[n] = beta[w * 32 + n * 16 + l15];
  }

  // ---- normalize + erf-GELU + transpose via LDS for coalesced NCHW stores
  #pragma unroll
  for (int n = 0; n < 2; ++n) {
    __syncthreads();
    #pragma unroll
    for (int m = 0; m < 4; ++m)
      #pragma unroll
      for (int r = 0; r < 4; ++r) {
        float v = (acc[m][n][r] - mean[m][r]) * rstd[m][r];
        v = v * gam[n] + bet[n];
        float ge = 0.5f * v * (1.f + erff(v * 0.70710678f));
        tbuf[w * 1040 + l15 * 65 + m * 16 + l4 * 4 + r] = ge;
      }
    __syncthreads();
    #pragma unroll
    for (int row = 0; row < 16; ++row) {
      float v = tbuf[w * 1040 + row * 65 + lane];
      const int o = w * 32 + n * 16 + row;
      out[(long)bidx * 802816 + (long)o * HW + hw0 + lane] = v;
    }
  }
}

// ---------------------------------------------------------------------------
extern "C" void kernel_launch(void* const* d_in, const int* in_sizes, int n_in,
                              void* d_out, int out_size, void* d_ws, size_t ws_size,
                              hipStream_t stream) {
  const float* x1    = (const float*)d_in[0];
  const float* x2    = (const float*)d_in[1];
  const float* W1    = (const float*)d_in[2];
  const float* W2    = (const float*)d_in[3];
  const float* Wp    = (const float*)d_in[4];
  const float* gamma = (const float*)d_in[5];
  const float* beta  = (const float*)d_in[6];
  float* out = (float*)d_out;

  // workspace layout
  float* P1T = (float*)d_ws;                          // 64 x 25088 f32 = 6,422,528 B
  u16*   P2b = (u16*)((char*)d_ws + 6422528);         // 25088 x 64 bf16 = 3,211,264 B
  u16*   Wpb = (u16*)((char*)d_ws + 9633792);         // 256 x 4096 bf16 = 2,097,152 B

  proj_kernel<<<dim3(708), dim3(256), 0, stream>>>(x1, x2, W1, W2, Wp, P1T, P2b, Wpb);
  bilinear_kernel<<<dim3(392), dim3(512), 0, stream>>>(P1T, P2b, Wpb, gamma, beta, out);
}